// Round 14
// baseline (220.724 us; speedup 1.0000x reference)
//
#include <hip/hip_runtime.h>
#include <math.h>

#define Bz 4
#define Lz 1500
#define Dz 512
#define NHz 8
#define Nz (Bz*Lz)       // 6000 rows
#define PEPSf 1.1920929e-07f

typedef __bf16 bf16x8 __attribute__((ext_vector_type(8)));
typedef unsigned short u16x8 __attribute__((ext_vector_type(8)));
typedef float f32x4 __attribute__((ext_vector_type(4)));
typedef unsigned short us;

__device__ __forceinline__ us f2bf(float f) {
  unsigned u = __float_as_uint(f);
  return (us)((u + 0x7fffu + ((u >> 16) & 1u)) >> 16);
}
__device__ __forceinline__ float bf2f(us b) {
  return __uint_as_float(((unsigned)b) << 16);
}
// tiled bf16 plane: P[((row/16)*64 + col/8)*128 + (row%16)*8 + col%8]
__device__ __forceinline__ int ti_idx(int row, int col) {
  return (((row >> 4) * 64 + (col >> 3)) << 7) + ((row & 15) << 3) + (col & 7);
}
__device__ __forceinline__ void st_tiled(us* __restrict__ P, int row, int col, us v) {
  P[ti_idx(row, col)] = v;
}

// XCD-swizzled block decode (94 row groups of 64 rows; ncg col groups)
__device__ __forceinline__ bool decode_blk(int bx, int ncg, int& R, int& cg) {
  int xcd = bx & 7, v = bx >> 3;
  cg = v % ncg;
  R = (v / ncg) * 8 + xcd;
  return R < 94;
}

// ---------------- phase 1 (merged): weights->planes + wq_eff planes  AND  row prep -------
// blocks [0,288): weight conversion units; blocks [288, 288+375): row prep, 16 rows/block.
// 16-rows-per-block matches the 16x8 tile: each block writes COMPLETE 256B tiles (no
// cross-block partial-line write amplification — R7->R11 verified: 222.4 -> 210.7 us).
__global__ __launch_bounds__(256) void k_prep(
    const float* __restrict__ hidden,
    const float* __restrict__ g, const float* __restrict__ bb,
    const float* __restrict__ s0, const float* __restrict__ s1, const float* __restrict__ s2,
    const float* __restrict__ s3,  // W1, W2, Wpv, Wpo
    const float* __restrict__ Wq, const float* __restrict__ Wk,
    const float* __restrict__ Wpk, const float* __restrict__ lq,
    us* __restrict__ h0, us* __restrict__ h1, us* __restrict__ h2, us* __restrict__ h3,
    us* __restrict__ l0, us* __restrict__ l1,
    us* __restrict__ WkTh, us* __restrict__ WkTl, us* __restrict__ WqTh, us* __restrict__ WqTl,
    us* __restrict__ wqeh, us* __restrict__ wqel,
    us* __restrict__ Uh, us* __restrict__ Ul, us* __restrict__ HNh, us* __restrict__ HNl) {
  const int t = threadIdx.x;
  if (blockIdx.x < 288) {
    const int u = blockIdx.x, rt = u & 31, mat = u >> 5;
    if (mat == 8) {  // wqe[h,d] = sum_e lq[h*64+e]*Wpk[h*64+e,d] -> tiled hi/lo plane row h
      if (rt < 8) {
        for (int d = t; d < Dz; d += 256) {
          float acc = 0.f;
          for (int e = 0; e < 64; ++e)
            acc += lq[rt * 64 + e] * Wpk[(size_t)(rt * 64 + e) * Dz + d];
          us hb = f2bf(acc);
          st_tiled(wqeh, rt, d, hb);
          st_tiled(wqel, rt, d, f2bf(acc - bf2f(hb)));
        }
      }
      return;
    }
    const float* S; us* H; us* L = nullptr; bool tr = false;
    switch (mat) {
      case 0: S = s0; H = h0; L = l0; break;            // W1 hi/lo
      case 1: S = s1; H = h1; L = l1; break;            // W2 hi/lo
      case 2: S = s2; H = h2; break;                    // Wpv hi
      case 3: S = s3; H = h3; break;                    // Wpo hi
      case 4: S = Wk; H = WkTh; L = WkTl; tr = true; break;  // Wk^T hi/lo
      default: S = Wq; H = WqTh; L = WqTl; tr = true; break; // Wq^T hi/lo
    }
    for (int e = t; e < 8192; e += 256) {
      int mm = e >> 9, c = e & 511;
      float x = tr ? S[(size_t)c * 512 + (rt * 16 + mm)]
                   : S[(size_t)(rt * 16 + mm) * 512 + c];
      us hb = f2bf(x);
      int off = ((rt * 64 + (c >> 3)) << 7) + (mm << 3) + (c & 7);
      H[off] = hb;
      if (L) L[off] = f2bf(x - bf2f(hb));
    }
    return;
  }
  // ---- row prep: block = 16-row tile group; 16 threads per row; u16x8 (16B) stores ----
  const int rb = blockIdx.x - 288;            // 0..374
  const int rl = t >> 4, sub = t & 15;        // row-in-group, 16 threads/row
  const int row = rb * 16 + rl;
  __shared__ float gs[Dz], bs[Dz];
  gs[t] = g[t]; gs[t + 256] = g[t + 256];
  bs[t] = bb[t]; bs[t + 256] = bb[t + 256];
  __syncthreads();
  const f32x4* xp = (const f32x4*)(hidden + (size_t)row * Dz + sub * 32);
  f32x4 xv[8];
  #pragma unroll
  for (int i = 0; i < 8; ++i) xv[i] = xp[i];
  float s = 0.f, q = 0.f;
  #pragma unroll
  for (int i = 0; i < 8; ++i)
    #pragma unroll
    for (int j = 0; j < 4; ++j) { float v = xv[i][j]; s += v; q += v * v; }
  #pragma unroll
  for (int o = 1; o < 16; o <<= 1) { s += __shfl_xor(s, o, 16); q += __shfl_xor(q, o, 16); }
  float un = 1.f / fmaxf(sqrtf(q), 1e-8f);
  float mu = s * (1.f / 512.f);
  float var = fmaxf(q * (1.f / 512.f) - mu * mu, 0.f);
  float r = rsqrtf(var + 1e-5f);
  const int rowoff = rl << 3;
  #pragma unroll
  for (int ch = 0; ch < 4; ++ch) {
    const int c0 = sub * 32 + ch * 8;
    u16x8 uh, ul, hh, hl;
    #pragma unroll
    for (int k = 0; k < 8; ++k) {
      float xx = xv[ch * 2 + (k >> 2)][k & 3];
      float u = xx * un;
      us b = f2bf(u);
      uh[k] = b; ul[k] = f2bf(u - bf2f(b));
      float hn = (xx - mu) * r * gs[c0 + k] + bs[c0 + k];
      us nb = f2bf(hn);
      hh[k] = nb; hl[k] = f2bf(hn - bf2f(nb));
    }
    const int off = ((rb * 64 + sub * 4 + ch) << 7) + rowoff;   // = ti_idx(row, c0)
    *(u16x8*)(Uh + off) = uh;
    *(u16x8*)(Ul + off) = ul;
    *(u16x8*)(HNh + off) = hh;
    *(u16x8*)(HNl + off) = hl;
  }
}

// ---------------- direct-layout MFMA GEMM body: 64x64 block tile, 32x32 wave tile --------
// no LDS, register prefetch; FULL K-loop unroll (R11: MfmaUtil 5-8% = latency-bound;
// unroll-2 limited the compiler's load-hoisting window to 1 step).
// outBase: skinny-output mode — stores v*0.125 to outBase[row*NHz+col] for col<NHz only.
template<int SPLIT>
__device__ __forceinline__ void gemm_body(
    const us* __restrict__ Ah, const us* __restrict__ Al,
    const us* __restrict__ Bh, const us* __restrict__ Bl,
    const float* __restrict__ bias,
    const us* __restrict__ addH, const us* __restrict__ addL, int doGelu,
    float* __restrict__ outF, us* __restrict__ outR,
    us* __restrict__ outH, us* __restrict__ outL, float* __restrict__ outBase,
    int R, int cg, int colbase, int Nrows) {
  const int t = threadIdx.x, w = t >> 6, l = t & 63;
  const int m = l & 15, q = l >> 4;
  const int wr = w & 1, wc = w >> 1;      // wave half-row / half-col within 64x64 tile
  const int laneoff = q * 128 + m * 8;
  const int nrtm1 = (Nrows >> 4) - 1;

  const u16x8* pa[2]; const u16x8* pal[2];
  const u16x8* pb[2]; const u16x8* pbl[2];
  #pragma unroll
  for (int i = 0; i < 2; ++i) {
    int rt = min(R * 4 + wr * 2 + i, nrtm1);   // tail clamp; stores guarded
    pa[i] = (const u16x8*)(Ah + (size_t)rt * 8192 + laneoff);
    if (SPLIT == 3) pal[i] = (const u16x8*)(Al + (size_t)rt * 8192 + laneoff);
  }
  #pragma unroll
  for (int j = 0; j < 2; ++j) {
    int ct = cg * 4 + wc * 2 + j;
    pb[j] = (const u16x8*)(Bh + (size_t)ct * 8192 + laneoff);
    if (SPLIT == 3) pbl[j] = (const u16x8*)(Bl + (size_t)ct * 8192 + laneoff);
  }

  u16x8 bAh[2][2], bAl[2][2], bBh[2][2], bBl[2][2];
  #pragma unroll
  for (int i = 0; i < 2; ++i) {
    bAh[0][i] = pa[i][0];
    if (SPLIT == 3) bAl[0][i] = pal[i][0];
  }
  #pragma unroll
  for (int j = 0; j < 2; ++j) {
    bBh[0][j] = pb[j][0];
    if (SPLIT == 3) bBl[0][j] = pbl[j][0];
  }

  f32x4 acc[2][2];
  #pragma unroll
  for (int i = 0; i < 2; ++i)
    #pragma unroll
    for (int j = 0; j < 2; ++j) acc[i][j] = (f32x4){0.f, 0.f, 0.f, 0.f};

  #pragma unroll
  for (int s = 0; s < 16; ++s) {
    const int cur = s & 1, nxt = cur ^ 1;
    const int sn = (s + 1) & 15;      // wrap: final iter reloads step 0 (discarded)
    #pragma unroll
    for (int i = 0; i < 2; ++i) {
      bAh[nxt][i] = pa[i][sn * 64];
      if (SPLIT == 3) bAl[nxt][i] = pal[i][sn * 64];
    }
    #pragma unroll
    for (int j = 0; j < 2; ++j) {
      bBh[nxt][j] = pb[j][sn * 64];
      if (SPLIT == 3) bBl[nxt][j] = pbl[j][sn * 64];
    }
    #pragma unroll
    for (int i = 0; i < 2; ++i)
      #pragma unroll
      for (int j = 0; j < 2; ++j) {
        bf16x8 a = __builtin_bit_cast(bf16x8, bAh[cur][i]);
        bf16x8 b = __builtin_bit_cast(bf16x8, bBh[cur][j]);
        acc[i][j] = __builtin_amdgcn_mfma_f32_16x16x32_bf16(a, b, acc[i][j], 0, 0, 0);
        if (SPLIT == 3) {
          bf16x8 al_ = __builtin_bit_cast(bf16x8, bAl[cur][i]);
          bf16x8 bl_ = __builtin_bit_cast(bf16x8, bBl[cur][j]);
          acc[i][j] = __builtin_amdgcn_mfma_f32_16x16x32_bf16(a, bl_, acc[i][j], 0, 0, 0);
          acc[i][j] = __builtin_amdgcn_mfma_f32_16x16x32_bf16(al_, b, acc[i][j], 0, 0, 0);
        }
      }
  }

  // epilogue: C/D layout col = m, row = q*4 + r
  const int row0 = R * 64 + wr * 32;
  const int col0 = colbase + wc * 32;
  #pragma unroll
  for (int i = 0; i < 2; ++i) {
    #pragma unroll
    for (int r = 0; r < 4; ++r) {
      const int grow = row0 + i * 16 + q * 4 + r;
      if (grow >= Nrows) continue;
      #pragma unroll
      for (int j = 0; j < 2; ++j) {
        const int gcol = col0 + j * 16 + m;
        float v = acc[i][j][r];
        if (outBase) {   // skinny base output: only first NHz cols are real
          if (gcol < NHz) outBase[(size_t)grow * NHz + gcol] = v * 0.125f;
          continue;
        }
        if (bias)   v += bias[gcol];
        if (addH) {
          int ai = ti_idx(grow, gcol);
          v += bf2f(addH[ai]) + bf2f(addL[ai]);
        }
        if (doGelu) v = 0.5f * v * (1.f + erff(v * 0.70710678118654752f));
        if (outF) outF[(size_t)grow * Dz + gcol] = v;
        if (outR) outR[(size_t)grow * Dz + gcol] = f2bf(v);
        if (outH) {
          us hb = f2bf(v);
          st_tiled(outH, grow, gcol, hb);
          if (outL) st_tiled(outL, grow, gcol, f2bf(v - bf2f(hb)));
        }
      }
    }
  }
}

// ---------------- phase 2: T1 (u<768), VALS (u<1536), Gt (u<1600), base GEMM (u<1694) ----
// base = (HN split-3) @ (wqe plane)^T, 64 cols computed, 8 stored.
__global__ __launch_bounds__(256, 4) void g_phase2(
    const us* Uh, const us* Ul, const us* W1h, const us* W1l, const float* b1, us* T1h, us* T1l,
    const us* HNh, const us* HNl, const us* Wpvh, us* VALSb,
    const us* WkTh, const us* WkTl, const us* WqTh, const us* WqTl, us* Gth, us* Gtl,
    const us* wqeh, const us* wqel, float* base) {
  const int u = blockIdx.x;
  if (u < 768) {
    int R, c;
    if (decode_blk(u, 8, R, c))
      gemm_body<3>(Uh, Ul, W1h, W1l, b1, nullptr, nullptr, 1,
                   nullptr, nullptr, T1h, T1l, nullptr, R, c, c * 64, Nz);
    return;
  }
  if (u < 1536) {
    int R, c;
    if (decode_blk(u - 768, 8, R, c))
      gemm_body<1>(HNh, nullptr, Wpvh, nullptr, nullptr, nullptr, nullptr, 0,
                   nullptr, VALSb, nullptr, nullptr, nullptr, R, c, c * 64, Nz);
    return;
  }
  if (u < 1600) {
    int bx = u - 1536;
    gemm_body<3>(WkTh, WkTl, WqTh, WqTl, nullptr, nullptr, nullptr, 0,
                 nullptr, nullptr, Gth, Gtl, nullptr, bx >> 3, bx & 7, (bx & 7) * 64, 512);
    return;
  }
  {  // base GEMM: 94 uniform blocks, single col group
    int R = u - 1600;
    if (R < 94)
      gemm_body<3>(HNh, HNl, wqeh, wqel, nullptr, nullptr, nullptr, 0,
                   nullptr, nullptr, nullptr, nullptr, base, R, 0, 0, Nz);
  }
}

// M = T1@W2^T + b2 + U  (fp32 + tiled hi/lo planes)
__global__ __launch_bounds__(256, 4) void g_w2(
    const us* T1h, const us* T1l, const us* W2h, const us* W2l, const float* b2,
    const us* Uh, const us* Ul, float* M, us* Mh, us* Ml) {
  int R, cg;
  if (!decode_blk(blockIdx.x, 8, R, cg)) return;
  gemm_body<3>(T1h, T1l, W2h, W2l, b2, Uh, Ul, 0, M, nullptr, Mh, Ml, nullptr,
               R, cg, cg * 64, Nz);
}

// P = M @ Gt^T   (normalization folded into k_probs)
__global__ __launch_bounds__(256, 4) void g_p(
    const us* Mh, const us* Ml, const us* Gth, const us* Gtl, float* P) {
  int R, cg;
  if (!decode_blk(blockIdx.x, 8, R, cg)) return;
  gemm_body<3>(Mh, Ml, Gth, Gtl, nullptr, nullptr, nullptr, 0,
               P, nullptr, nullptr, nullptr, nullptr, R, cg, cg * 64, Nz);
}

__global__ __launch_bounds__(256, 4) void g_out(
    const us* Ph, const us* Wpoh, float* out) {
  int R, cg;
  if (!decode_blk(blockIdx.x, 8, R, cg)) return;
  gemm_body<1>(Ph, nullptr, Wpoh, nullptr, nullptr, nullptr, nullptr, 0,
               out, nullptr, nullptr, nullptr, nullptr, R, cg, cg * 64, Nz);
}

// ---------------- cos(l) = un_l * un_{l+1} * dot(P_l, M_{l+1}) -> probs ----------------
__global__ __launch_bounds__(256) void k_probs(const float* __restrict__ P,
    const float* __restrict__ M, const float* __restrict__ simb,
    float* __restrict__ probs) {
  const int w = threadIdx.x >> 6, t = threadIdx.x & 63;
  const int l = blockIdx.x * 4 + w, b = blockIdx.y;
  if (l >= Lz) return;
  if (l == Lz - 1) { if (t == 0) probs[(size_t)b * Lz + l] = 0.f; return; }
  const float* pp = P + ((size_t)b * Lz + l) * Dz;
  const float* m0 = M + ((size_t)b * Lz + l) * Dz;
  const float* m1 = M + ((size_t)b * Lz + l + 1) * Dz;
  float accd = 0.f, q0 = 0.f, q1 = 0.f;
  for (int i = t; i < Dz; i += 64) {
    float a = pp[i], x0 = m0[i], x1 = m1[i];
    accd += a * x1; q0 += x0 * x0; q1 += x1 * x1;
  }
  #pragma unroll
  for (int o = 32; o > 0; o >>= 1) {
    accd += __shfl_xor(accd, o, 64);
    q0 += __shfl_xor(q0, o, 64);
    q1 += __shfl_xor(q1, o, 64);
  }
  if (t == 0) {
    float un0 = 1.f / fmaxf(sqrtf(q0), 1e-8f);
    float un1 = 1.f / fmaxf(sqrtf(q1), 1e-8f);
    float cosv = accd * un0 * un1;
    float p = (1.f - (cosv + simb[0])) * 0.5f;
    probs[(size_t)b * Lz + l] = fminf(fmaxf(p, 0.f), 1.f);
  }
}

// ---------------- boundaries + scan (shuffle-based scan) ----------------
__global__ __launch_bounds__(256) void k_boundary(const float* __restrict__ probs,
    const float* __restrict__ un, const float* __restrict__ lengths,
    int* __restrict__ seg_start, int* __restrict__ seg_meta) {
  const int b = blockIdx.x, t = threadIdx.x;
  __shared__ float hard[Lz];
  __shared__ float ws4[4];
  __shared__ float wsum[4];
  const float len = lengths[b];
  const int valid_len = min((int)(len * (Lz + 1)) - 1, Lz);
  const int Lm = (int)(len * Lz);
  const bool trunc = valid_len < Lz;
  for (int l = t; l < Lz; l += 256) {
    float p = probs[(size_t)b * Lz + l];
    p = fminf(fmaxf(p, PEPSf), 1.f - PEPSf);
    float u = un[(size_t)b * Lz + l];
    u = fminf(fmaxf(u, PEPSf), 1.f - PEPSf);
    float z = logf(p) - log1pf(-p) + logf(u) - log1pf(-u);
    float soft = 1.f / (1.f + expf(-z));
    float hd = soft > 0.5f ? 1.f : 0.f;
    if (trunc && l >= valid_len) hd = (l == valid_len) ? 1.f : 0.f;
    hard[l] = hd;
  }
  __syncthreads();
  float sm = 0.f;
  for (int l = t; l < Lz; l += 256) sm += hard[l];
  #pragma unroll
  for (int o = 32; o > 0; o >>= 1) sm += __shfl_xor(sm, o, 64);
  if ((t & 63) == 0) ws4[t >> 6] = sm;
  __syncthreads();
  float total = ws4[0] + ws4[1] + ws4[2] + ws4[3];
  if (total == 0.f && t == 0) hard[min(valid_len, Lz - 1)] = 1.f;
  __syncthreads();
  const int l0 = t * 6;
  float loc = 0.f;
  for (int i = 0; i < 6; ++i) { int l = l0 + i; if (l < Lz) loc += hard[l]; }
  const int wid = t >> 6, lane = t & 63;
  float v = loc;
  #pragma unroll
  for (int o = 1; o < 64; o <<= 1) {
    float n = __shfl_up(v, o, 64);
    if (lane >= o) v += n;
  }
  if (lane == 63) wsum[wid] = v;
  __syncthreads();
  float woff = 0.f;
  for (int ww = 0; ww < wid; ++ww) woff += wsum[ww];
  float run = v + woff - loc;          // exclusive prefix (exact: integer-valued fp32)
  for (int i = 0; i < 6; ++i) {
    int l = l0 + i; if (l >= Lz) break;
    int seg = (int)(run + 0.5f);
    if (l == 0) seg_start[b * (Lz + 1) + 0] = 0;
    else if (hard[l - 1] > 0.5f) seg_start[b * (Lz + 1) + seg] = l;
    if (l == Lz - 1) {
      int nseg = seg + 1;
      seg_meta[b * 2 + 0] = nseg;
      seg_meta[b * 2 + 1] = Lm;
      seg_start[b * (Lz + 1) + nseg] = Lz;
    }
    run += hard[l];
  }
}

// ---------------- segment softmax-pool (VALS bf16 row-major) -> POOLED hi plane ----------
__global__ __launch_bounds__(256) void k_pool(const float* __restrict__ base,
    const us* __restrict__ VALSb, const int* __restrict__ seg_start,
    const int* __restrict__ seg_meta, us* __restrict__ Ph) {
  const int s = blockIdx.x, b = blockIdx.y, t = threadIdx.x;
  const int orow = b * Lz + s;
  const int nseg = seg_meta[b * 2], Lm = seg_meta[b * 2 + 1];
  int start = 0, end = 0;
  bool empty = true;
  if (s < nseg) {
    start = seg_start[b * (Lz + 1) + s];
    end = min(seg_start[b * (Lz + 1) + s + 1], Lm);
    empty = start >= end;
  }
  if (empty) { st_tiled(Ph, orow, t, 0); st_tiled(Ph, orow, t + 256, 0); return; }
  const int h = t >> 5, lane = t & 31;
  const float* bp = base + (size_t)b * Lz * NHz + h;
  float m = -1e30f;
  for (int l = start + lane; l < end; l += 32) m = fmaxf(m, bp[(size_t)l * NHz]);
  #pragma unroll
  for (int o = 16; o > 0; o >>= 1) m = fmaxf(m, __shfl_xor(m, o, 32));
  float den = 0.f;
  for (int l = start + lane; l < end; l += 32) den += expf(bp[(size_t)l * NHz] - m);
  #pragma unroll
  for (int o = 16; o > 0; o >>= 1) den += __shfl_xor(den, o, 32);
  float a0 = 0.f, a1 = 0.f;
  const us* vp = VALSb + (size_t)b * Lz * Dz + h * 64 + lane;
  for (int l = start; l < end; ++l) {
    float wgt = expf(bp[(size_t)l * NHz] - m);
    a0 += wgt * bf2f(vp[(size_t)l * Dz]);
    a1 += wgt * bf2f(vp[(size_t)l * Dz + 32]);
  }
  float inv = 1.f / den;
  st_tiled(Ph, orow, h * 64 + lane, f2bf(a0 * inv));
  st_tiled(Ph, orow, h * 64 + lane + 32, f2bf(a1 * inv));
}

extern "C" void kernel_launch(void* const* d_in, const int* in_sizes, int n_in,
                              void* d_out, int out_size, void* d_ws, size_t ws_size,
                              hipStream_t stream) {
  const float* hidden  = (const float*)d_in[0];
  const float* lengths = (const float*)d_in[1];
  const float* unoise  = (const float*)d_in[2];
  const float* W1  = (const float*)d_in[3];
  const float* b1  = (const float*)d_in[4];
  const float* W2  = (const float*)d_in[5];
  const float* b2  = (const float*)d_in[6];
  const float* Wq  = (const float*)d_in[7];
  const float* Wk  = (const float*)d_in[8];
  const float* simb   = (const float*)d_in[9];
  const float* lquery = (const float*)d_in[10];
  const float* Wpk = (const float*)d_in[11];
  const float* Wpv = (const float*)d_in[12];
  const float* Wpo = (const float*)d_in[13];
  const float* lng = (const float*)d_in[14];
  const float* lnb = (const float*)d_in[15];
  float* out = (float*)d_out;

  char* p = (char*)d_ws;
  const size_t SF = (size_t)Nz * Dz * 4;          // 12,288,000 B
  const size_t TP = (size_t)376 * 8192 * 2;       // 6,160,384 B
  const size_t WP = (size_t)32 * 8192 * 2;        // 524,288 B
  const size_t QP = (size_t)4 * 8192 * 2;         // 65,536 B (64x512 plane)
  float* M    = (float*)p; p += SF;
  float* PF   = (float*)p; p += SF;
  us* VALSb = (us*)p; p += TP;   // row-major bf16 (Nz*Dz*2 = 6,144,000 <= TP)
  us* Uh  = (us*)p; p += TP;
  us* Ul  = (us*)p; p += TP;
  us* T1h = (us*)p; p += TP;
  us* T1l = (us*)p; p += TP;
  us* Mh  = (us*)p; p += TP;
  us* Ml  = (us*)p; p += TP;
  us* HNh = (us*)p; p += TP;
  us* HNl = (us*)p; p += TP;
  us* Ph  = (us*)p; p += TP;
  us* W1h = (us*)p; p += WP;
  us* W1l = (us*)p; p += WP;
  us* W2h = (us*)p; p += WP;
  us* W2l = (us*)p; p += WP;
  us* Wpvh = (us*)p; p += WP;
  us* Wpoh = (us*)p; p += WP;
  us* WkTh = (us*)p; p += WP;
  us* WkTl = (us*)p; p += WP;
  us* WqTh = (us*)p; p += WP;
  us* WqTl = (us*)p; p += WP;
  us* Gth  = (us*)p; p += WP;
  us* Gtl  = (us*)p; p += WP;
  us* wqeh = (us*)p; p += QP;
  us* wqel = (us*)p; p += QP;
  float* probs  = (float*)p; p += 24064;
  float* base   = (float*)p; p += 192000;
  int* segst    = (int*)p;   p += 24064;
  int* segmeta  = (int*)p;   p += 256;

  const int G8 = 8 * 12 * 8;   // 768 swizzle slots (752 used), 64x64 tiles

  k_prep<<<288 + 375, 256, 0, stream>>>(hidden, lng, lnb, W1, W2, Wpv, Wpo, Wq, Wk,
      Wpk, lquery, W1h, W2h, Wpvh, Wpoh, W1l, W2l, WkTh, WkTl, WqTh, WqTl,
      wqeh, wqel, Uh, Ul, HNh, HNl);
  g_phase2<<<1694, 256, 0, stream>>>(Uh, Ul, W1h, W1l, b1, T1h, T1l,
      HNh, HNl, Wpvh, VALSb, WkTh, WkTl, WqTh, WqTl, Gth, Gtl, wqeh, wqel, base);
  g_w2<<<G8, 256, 0, stream>>>(T1h, T1l, W2h, W2l, b2, Uh, Ul, M, Mh, Ml);  // M(+planes)
  g_p<<<G8, 256, 0, stream>>>(Mh, Ml, Gth, Gtl, PF);             // P = M@Gt^T
  k_probs<<<dim3(375, Bz), 256, 0, stream>>>(PF, M, simb, probs);
  k_boundary<<<Bz, 256, 0, stream>>>(probs, unoise, lengths, segst, segmeta);
  k_pool<<<dim3(Lz, Bz), 256, 0, stream>>>(base, VALSb, segst, segmeta, Ph);
  g_out<<<G8, 256, 0, stream>>>(Ph, Wpoh, out);                  // out = POOLED@Wpo^T
}

// Round 15
// 212.272 us; speedup vs baseline: 1.0398x; 1.0398x over previous
//
#include <hip/hip_runtime.h>
#include <math.h>

#define Bz 4
#define Lz 1500
#define Dz 512
#define NHz 8
#define Nz (Bz*Lz)       // 6000 rows
#define PEPSf 1.1920929e-07f

typedef __bf16 bf16x8 __attribute__((ext_vector_type(8)));
typedef unsigned short u16x8 __attribute__((ext_vector_type(8)));
typedef float f32x4 __attribute__((ext_vector_type(4)));
typedef unsigned short us;

#define LDS_STRIDE 72   // us; multiple of 8 (16B-aligned u16x8 rows), 144B = 36 dw banks

__device__ __forceinline__ us f2bf(float f) {
  unsigned u = __float_as_uint(f);
  return (us)((u + 0x7fffu + ((u >> 16) & 1u)) >> 16);
}
__device__ __forceinline__ float bf2f(us b) {
  return __uint_as_float(((unsigned)b) << 16);
}
// tiled bf16 plane: P[((row/16)*64 + col/8)*128 + (row%16)*8 + col%8]
__device__ __forceinline__ int ti_idx(int row, int col) {
  return (((row >> 4) * 64 + (col >> 3)) << 7) + ((row & 15) << 3) + (col & 7);
}
__device__ __forceinline__ void st_tiled(us* __restrict__ P, int row, int col, us v) {
  P[ti_idx(row, col)] = v;
}

// XCD-swizzled block decode (94 row groups of 64 rows; ncg col groups)
__device__ __forceinline__ bool decode_blk(int bx, int ncg, int& R, int& cg) {
  int xcd = bx & 7, v = bx >> 3;
  cg = v % ncg;
  R = (v / ncg) * 8 + xcd;
  return R < 94;
}

// ---------------- phase 1 (merged): weights->planes + wq_eff planes  AND  row prep -------
// blocks [0,288): weight conversion units; blocks [288, 288+375): row prep, 16 rows/block.
// 16-rows-per-block matches the 16x8 tile: each block writes COMPLETE 256B tiles (no
// cross-block partial-line write amplification — R7->R11 verified: 222.4 -> 210.7 us).
__global__ __launch_bounds__(256) void k_prep(
    const float* __restrict__ hidden,
    const float* __restrict__ g, const float* __restrict__ bb,
    const float* __restrict__ s0, const float* __restrict__ s1, const float* __restrict__ s2,
    const float* __restrict__ s3,  // W1, W2, Wpv, Wpo
    const float* __restrict__ Wq, const float* __restrict__ Wk,
    const float* __restrict__ Wpk, const float* __restrict__ lq,
    us* __restrict__ h0, us* __restrict__ h1, us* __restrict__ h2, us* __restrict__ h3,
    us* __restrict__ l0, us* __restrict__ l1,
    us* __restrict__ WkTh, us* __restrict__ WkTl, us* __restrict__ WqTh, us* __restrict__ WqTl,
    us* __restrict__ wqeh, us* __restrict__ wqel,
    us* __restrict__ Uh, us* __restrict__ Ul, us* __restrict__ HNh, us* __restrict__ HNl) {
  const int t = threadIdx.x;
  if (blockIdx.x < 288) {
    const int u = blockIdx.x, rt = u & 31, mat = u >> 5;
    if (mat == 8) {  // wqe[h,d] = sum_e lq[h*64+e]*Wpk[h*64+e,d] -> tiled hi/lo plane row h
      if (rt < 8) {
        for (int d = t; d < Dz; d += 256) {
          float acc = 0.f;
          for (int e = 0; e < 64; ++e)
            acc += lq[rt * 64 + e] * Wpk[(size_t)(rt * 64 + e) * Dz + d];
          us hb = f2bf(acc);
          st_tiled(wqeh, rt, d, hb);
          st_tiled(wqel, rt, d, f2bf(acc - bf2f(hb)));
        }
      }
      return;
    }
    const float* S; us* H; us* L = nullptr; bool tr = false;
    switch (mat) {
      case 0: S = s0; H = h0; L = l0; break;            // W1 hi/lo
      case 1: S = s1; H = h1; L = l1; break;            // W2 hi/lo
      case 2: S = s2; H = h2; break;                    // Wpv hi
      case 3: S = s3; H = h3; break;                    // Wpo hi
      case 4: S = Wk; H = WkTh; L = WkTl; tr = true; break;  // Wk^T hi/lo
      default: S = Wq; H = WqTh; L = WqTl; tr = true; break; // Wq^T hi/lo
    }
    for (int e = t; e < 8192; e += 256) {
      int mm = e >> 9, c = e & 511;
      float x = tr ? S[(size_t)c * 512 + (rt * 16 + mm)]
                   : S[(size_t)(rt * 16 + mm) * 512 + c];
      us hb = f2bf(x);
      int off = ((rt * 64 + (c >> 3)) << 7) + (mm << 3) + (c & 7);
      H[off] = hb;
      if (L) L[off] = f2bf(x - bf2f(hb));
    }
    return;
  }
  // ---- row prep: block = 16-row tile group; 16 threads per row; u16x8 (16B) stores ----
  const int rb = blockIdx.x - 288;            // 0..374
  const int rl = t >> 4, sub = t & 15;        // row-in-group, 16 threads/row
  const int row = rb * 16 + rl;
  __shared__ float gs[Dz], bs[Dz];
  gs[t] = g[t]; gs[t + 256] = g[t + 256];
  bs[t] = bb[t]; bs[t + 256] = bb[t + 256];
  __syncthreads();
  const f32x4* xp = (const f32x4*)(hidden + (size_t)row * Dz + sub * 32);
  f32x4 xv[8];
  #pragma unroll
  for (int i = 0; i < 8; ++i) xv[i] = xp[i];
  float s = 0.f, q = 0.f;
  #pragma unroll
  for (int i = 0; i < 8; ++i)
    #pragma unroll
    for (int j = 0; j < 4; ++j) { float v = xv[i][j]; s += v; q += v * v; }
  #pragma unroll
  for (int o = 1; o < 16; o <<= 1) { s += __shfl_xor(s, o, 16); q += __shfl_xor(q, o, 16); }
  float un = 1.f / fmaxf(sqrtf(q), 1e-8f);
  float mu = s * (1.f / 512.f);
  float var = fmaxf(q * (1.f / 512.f) - mu * mu, 0.f);
  float r = rsqrtf(var + 1e-5f);
  const int rowoff = rl << 3;
  #pragma unroll
  for (int ch = 0; ch < 4; ++ch) {
    const int c0 = sub * 32 + ch * 8;
    u16x8 uh, ul, hh, hl;
    #pragma unroll
    for (int k = 0; k < 8; ++k) {
      float xx = xv[ch * 2 + (k >> 2)][k & 3];
      float u = xx * un;
      us b = f2bf(u);
      uh[k] = b; ul[k] = f2bf(u - bf2f(b));
      float hn = (xx - mu) * r * gs[c0 + k] + bs[c0 + k];
      us nb = f2bf(hn);
      hh[k] = nb; hl[k] = f2bf(hn - bf2f(nb));
    }
    const int off = ((rb * 64 + sub * 4 + ch) << 7) + rowoff;   // = ti_idx(row, c0)
    *(u16x8*)(Uh + off) = uh;
    *(u16x8*)(Ul + off) = ul;
    *(u16x8*)(HNh + off) = hh;
    *(u16x8*)(HNl + off) = hl;
  }
}

// ---------------- direct-layout MFMA GEMM body: 64x64 block tile, 32x32 wave tile --------
// no LDS operands, 1-deep register prefetch, unroll-2 (R14: full unroll regressed 210->221).
// Tiled-plane outputs (outH/outL) are LDS-staged then written as complete 256B tiles
// (coalesced 32B/thread) — same write-amplification fix class as k_prep (R7->R11).
// outBase: skinny-output mode — stores v*0.125 to outBase[row*NHz+col] for col<NHz only.
template<int SPLIT>
__device__ __forceinline__ void gemm_body(
    const us* __restrict__ Ah, const us* __restrict__ Al,
    const us* __restrict__ Bh, const us* __restrict__ Bl,
    const float* __restrict__ bias,
    const us* __restrict__ addH, const us* __restrict__ addL, int doGelu,
    float* __restrict__ outF, us* __restrict__ outR,
    us* __restrict__ outH, us* __restrict__ outL, float* __restrict__ outBase,
    us* __restrict__ ldsH, us* __restrict__ ldsL,
    int R, int cg, int colbase, int Nrows) {
  const int t = threadIdx.x, w = t >> 6, l = t & 63;
  const int m = l & 15, q = l >> 4;
  const int wr = w & 1, wc = w >> 1;      // wave half-row / half-col within 64x64 tile
  const int laneoff = q * 128 + m * 8;
  const int nrtm1 = (Nrows >> 4) - 1;

  const u16x8* pa[2]; const u16x8* pal[2];
  const u16x8* pb[2]; const u16x8* pbl[2];
  #pragma unroll
  for (int i = 0; i < 2; ++i) {
    int rt = min(R * 4 + wr * 2 + i, nrtm1);   // tail clamp; stores guarded
    pa[i] = (const u16x8*)(Ah + (size_t)rt * 8192 + laneoff);
    if (SPLIT == 3) pal[i] = (const u16x8*)(Al + (size_t)rt * 8192 + laneoff);
  }
  #pragma unroll
  for (int j = 0; j < 2; ++j) {
    int ct = cg * 4 + wc * 2 + j;
    pb[j] = (const u16x8*)(Bh + (size_t)ct * 8192 + laneoff);
    if (SPLIT == 3) pbl[j] = (const u16x8*)(Bl + (size_t)ct * 8192 + laneoff);
  }

  u16x8 bAh[2][2], bAl[2][2], bBh[2][2], bBl[2][2];
  #pragma unroll
  for (int i = 0; i < 2; ++i) {
    bAh[0][i] = pa[i][0];
    if (SPLIT == 3) bAl[0][i] = pal[i][0];
  }
  #pragma unroll
  for (int j = 0; j < 2; ++j) {
    bBh[0][j] = pb[j][0];
    if (SPLIT == 3) bBl[0][j] = pbl[j][0];
  }

  f32x4 acc[2][2];
  #pragma unroll
  for (int i = 0; i < 2; ++i)
    #pragma unroll
    for (int j = 0; j < 2; ++j) acc[i][j] = (f32x4){0.f, 0.f, 0.f, 0.f};

  #pragma unroll 2
  for (int s = 0; s < 16; ++s) {
    const int cur = s & 1, nxt = cur ^ 1;
    const int sn = (s + 1) & 15;      // wrap: final iter reloads step 0 (discarded)
    #pragma unroll
    for (int i = 0; i < 2; ++i) {
      bAh[nxt][i] = pa[i][sn * 64];
      if (SPLIT == 3) bAl[nxt][i] = pal[i][sn * 64];
    }
    #pragma unroll
    for (int j = 0; j < 2; ++j) {
      bBh[nxt][j] = pb[j][sn * 64];
      if (SPLIT == 3) bBl[nxt][j] = pbl[j][sn * 64];
    }
    #pragma unroll
    for (int i = 0; i < 2; ++i)
      #pragma unroll
      for (int j = 0; j < 2; ++j) {
        bf16x8 a = __builtin_bit_cast(bf16x8, bAh[cur][i]);
        bf16x8 b = __builtin_bit_cast(bf16x8, bBh[cur][j]);
        acc[i][j] = __builtin_amdgcn_mfma_f32_16x16x32_bf16(a, b, acc[i][j], 0, 0, 0);
        if (SPLIT == 3) {
          bf16x8 al_ = __builtin_bit_cast(bf16x8, bAl[cur][i]);
          bf16x8 bl_ = __builtin_bit_cast(bf16x8, bBl[cur][j]);
          acc[i][j] = __builtin_amdgcn_mfma_f32_16x16x32_bf16(a, bl_, acc[i][j], 0, 0, 0);
          acc[i][j] = __builtin_amdgcn_mfma_f32_16x16x32_bf16(al_, b, acc[i][j], 0, 0, 0);
        }
      }
  }

  // epilogue: C/D layout col = m, row = q*4 + r
  const int row0 = R * 64 + wr * 32;
  const int col0 = colbase + wc * 32;
  const int lrow0 = wr * 32, lcol0 = wc * 32;
  #pragma unroll
  for (int i = 0; i < 2; ++i) {
    #pragma unroll
    for (int r = 0; r < 4; ++r) {
      const int grow = row0 + i * 16 + q * 4 + r;
      const int lrow = lrow0 + i * 16 + q * 4 + r;
      #pragma unroll
      for (int j = 0; j < 2; ++j) {
        const int gcol = col0 + j * 16 + m;
        float v = acc[i][j][r];
        if (outBase) {   // skinny base output: only first NHz cols are real
          if (gcol < NHz && grow < Nrows) outBase[(size_t)grow * NHz + gcol] = v * 0.125f;
          continue;
        }
        if (bias)   v += bias[gcol];
        if (addH) {
          int ai = ti_idx(grow, gcol);   // tail rows read tile 375 scratch (allocated)
          v += bf2f(addH[ai]) + bf2f(addL[ai]);
        }
        if (doGelu) v = 0.5f * v * (1.f + erff(v * 0.70710678118654752f));
        if (outF && grow < Nrows) outF[(size_t)grow * Dz + gcol] = v;
        if (outR && grow < Nrows) outR[(size_t)grow * Dz + gcol] = f2bf(v);
        if (outH) {   // stage to LDS; tail rows land in never-read tile 375 region
          us hb = f2bf(v);
          const int li = lrow * LDS_STRIDE + lcol0 + j * 16 + m;
          ldsH[li] = hb;
          ldsL[li] = f2bf(v - bf2f(hb));
        }
      }
    }
  }
  if (outH) {   // coalesced copy-out: thread t -> tile t>>3, 32B segment (t&7)*16
    __syncthreads();
    const int tile = t >> 3, seg = t & 7;
    const int tr = tile >> 3, tc = tile & 7;
    const int gt = (((R * 4 + tr) * 64 + (colbase >> 3) + tc) << 7) + seg * 16;
    const int lr = tr * 16 + seg * 2;
    const us* sH = ldsH + lr * LDS_STRIDE + tc * 8;
    const us* sL = ldsL + lr * LDS_STRIDE + tc * 8;
    *(u16x8*)(outH + gt)     = *(const u16x8*)sH;
    *(u16x8*)(outH + gt + 8) = *(const u16x8*)(sH + LDS_STRIDE);
    *(u16x8*)(outL + gt)     = *(const u16x8*)sL;
    *(u16x8*)(outL + gt + 8) = *(const u16x8*)(sL + LDS_STRIDE);
  }
}

// ---------------- phase 2: T1 (u<768), VALS (u<1536), Gt (u<1600), base GEMM (u<1694) ----
// base = (HN split-3) @ (wqe plane)^T, 64 cols computed, 8 stored.
__global__ __launch_bounds__(256, 4) void g_phase2(
    const us* Uh, const us* Ul, const us* W1h, const us* W1l, const float* b1, us* T1h, us* T1l,
    const us* HNh, const us* HNl, const us* Wpvh, us* VALSb,
    const us* WkTh, const us* WkTl, const us* WqTh, const us* WqTl, us* Gth, us* Gtl,
    const us* wqeh, const us* wqel, float* base) {
  __shared__ us ldsH[64 * LDS_STRIDE], ldsL[64 * LDS_STRIDE];
  const int u = blockIdx.x;
  if (u < 768) {
    int R, c;
    if (decode_blk(u, 8, R, c))
      gemm_body<3>(Uh, Ul, W1h, W1l, b1, nullptr, nullptr, 1,
                   nullptr, nullptr, T1h, T1l, nullptr, ldsH, ldsL, R, c, c * 64, Nz);
    return;
  }
  if (u < 1536) {
    int R, c;
    if (decode_blk(u - 768, 8, R, c))
      gemm_body<1>(HNh, nullptr, Wpvh, nullptr, nullptr, nullptr, nullptr, 0,
                   nullptr, VALSb, nullptr, nullptr, nullptr, nullptr, nullptr,
                   R, c, c * 64, Nz);
    return;
  }
  if (u < 1600) {
    int bx = u - 1536;
    gemm_body<3>(WkTh, WkTl, WqTh, WqTl, nullptr, nullptr, nullptr, 0,
                 nullptr, nullptr, Gth, Gtl, nullptr, ldsH, ldsL,
                 bx >> 3, bx & 7, (bx & 7) * 64, 512);
    return;
  }
  {  // base GEMM: 94 uniform blocks, single col group
    int R = u - 1600;
    if (R < 94)
      gemm_body<3>(HNh, HNl, wqeh, wqel, nullptr, nullptr, nullptr, 0,
                   nullptr, nullptr, nullptr, nullptr, base, nullptr, nullptr,
                   R, 0, 0, Nz);
  }
}

// M = T1@W2^T + b2 + U  (fp32 + tiled hi/lo planes)
__global__ __launch_bounds__(256, 4) void g_w2(
    const us* T1h, const us* T1l, const us* W2h, const us* W2l, const float* b2,
    const us* Uh, const us* Ul, float* M, us* Mh, us* Ml) {
  __shared__ us ldsH[64 * LDS_STRIDE], ldsL[64 * LDS_STRIDE];
  int R, cg;
  if (!decode_blk(blockIdx.x, 8, R, cg)) return;
  gemm_body<3>(T1h, T1l, W2h, W2l, b2, Uh, Ul, 0, M, nullptr, Mh, Ml, nullptr,
               ldsH, ldsL, R, cg, cg * 64, Nz);
}

// P = M @ Gt^T   (normalization folded into k_probs)
__global__ __launch_bounds__(256, 4) void g_p(
    const us* Mh, const us* Ml, const us* Gth, const us* Gtl, float* P) {
  int R, cg;
  if (!decode_blk(blockIdx.x, 8, R, cg)) return;
  gemm_body<3>(Mh, Ml, Gth, Gtl, nullptr, nullptr, nullptr, 0,
               P, nullptr, nullptr, nullptr, nullptr, nullptr, nullptr,
               R, cg, cg * 64, Nz);
}

__global__ __launch_bounds__(256, 4) void g_out(
    const us* Ph, const us* Wpoh, float* out) {
  int R, cg;
  if (!decode_blk(blockIdx.x, 8, R, cg)) return;
  gemm_body<1>(Ph, nullptr, Wpoh, nullptr, nullptr, nullptr, nullptr, 0,
               out, nullptr, nullptr, nullptr, nullptr, nullptr, nullptr,
               R, cg, cg * 64, Nz);
}

// ---------------- cos(l) = un_l * un_{l+1} * dot(P_l, M_{l+1}) -> probs ----------------
__global__ __launch_bounds__(256) void k_probs(const float* __restrict__ P,
    const float* __restrict__ M, const float* __restrict__ simb,
    float* __restrict__ probs) {
  const int w = threadIdx.x >> 6, t = threadIdx.x & 63;
  const int l = blockIdx.x * 4 + w, b = blockIdx.y;
  if (l >= Lz) return;
  if (l == Lz - 1) { if (t == 0) probs[(size_t)b * Lz + l] = 0.f; return; }
  const float* pp = P + ((size_t)b * Lz + l) * Dz;
  const float* m0 = M + ((size_t)b * Lz + l) * Dz;
  const float* m1 = M + ((size_t)b * Lz + l + 1) * Dz;
  float accd = 0.f, q0 = 0.f, q1 = 0.f;
  for (int i = t; i < Dz; i += 64) {
    float a = pp[i], x0 = m0[i], x1 = m1[i];
    accd += a * x1; q0 += x0 * x0; q1 += x1 * x1;
  }
  #pragma unroll
  for (int o = 32; o > 0; o >>= 1) {
    accd += __shfl_xor(accd, o, 64);
    q0 += __shfl_xor(q0, o, 64);
    q1 += __shfl_xor(q1, o, 64);
  }
  if (t == 0) {
    float un0 = 1.f / fmaxf(sqrtf(q0), 1e-8f);
    float un1 = 1.f / fmaxf(sqrtf(q1), 1e-8f);
    float cosv = accd * un0 * un1;
    float p = (1.f - (cosv + simb[0])) * 0.5f;
    probs[(size_t)b * Lz + l] = fminf(fmaxf(p, 0.f), 1.f);
  }
}

// ---------------- boundaries + scan (shuffle-based scan) ----------------
__global__ __launch_bounds__(256) void k_boundary(const float* __restrict__ probs,
    const float* __restrict__ un, const float* __restrict__ lengths,
    int* __restrict__ seg_start, int* __restrict__ seg_meta) {
  const int b = blockIdx.x, t = threadIdx.x;
  __shared__ float hard[Lz];
  __shared__ float ws4[4];
  __shared__ float wsum[4];
  const float len = lengths[b];
  const int valid_len = min((int)(len * (Lz + 1)) - 1, Lz);
  const int Lm = (int)(len * Lz);
  const bool trunc = valid_len < Lz;
  for (int l = t; l < Lz; l += 256) {
    float p = probs[(size_t)b * Lz + l];
    p = fminf(fmaxf(p, PEPSf), 1.f - PEPSf);
    float u = un[(size_t)b * Lz + l];
    u = fminf(fmaxf(u, PEPSf), 1.f - PEPSf);
    float z = logf(p) - log1pf(-p) + logf(u) - log1pf(-u);
    float soft = 1.f / (1.f + expf(-z));
    float hd = soft > 0.5f ? 1.f : 0.f;
    if (trunc && l >= valid_len) hd = (l == valid_len) ? 1.f : 0.f;
    hard[l] = hd;
  }
  __syncthreads();
  float sm = 0.f;
  for (int l = t; l < Lz; l += 256) sm += hard[l];
  #pragma unroll
  for (int o = 32; o > 0; o >>= 1) sm += __shfl_xor(sm, o, 64);
  if ((t & 63) == 0) ws4[t >> 6] = sm;
  __syncthreads();
  float total = ws4[0] + ws4[1] + ws4[2] + ws4[3];
  if (total == 0.f && t == 0) hard[min(valid_len, Lz - 1)] = 1.f;
  __syncthreads();
  const int l0 = t * 6;
  float loc = 0.f;
  for (int i = 0; i < 6; ++i) { int l = l0 + i; if (l < Lz) loc += hard[l]; }
  const int wid = t >> 6, lane = t & 63;
  float v = loc;
  #pragma unroll
  for (int o = 1; o < 64; o <<= 1) {
    float n = __shfl_up(v, o, 64);
    if (lane >= o) v += n;
  }
  if (lane == 63) wsum[wid] = v;
  __syncthreads();
  float woff = 0.f;
  for (int ww = 0; ww < wid; ++ww) woff += wsum[ww];
  float run = v + woff - loc;          // exclusive prefix (exact: integer-valued fp32)
  for (int i = 0; i < 6; ++i) {
    int l = l0 + i; if (l >= Lz) break;
    int seg = (int)(run + 0.5f);
    if (l == 0) seg_start[b * (Lz + 1) + 0] = 0;
    else if (hard[l - 1] > 0.5f) seg_start[b * (Lz + 1) + seg] = l;
    if (l == Lz - 1) {
      int nseg = seg + 1;
      seg_meta[b * 2 + 0] = nseg;
      seg_meta[b * 2 + 1] = Lm;
      seg_start[b * (Lz + 1) + nseg] = Lz;
    }
    run += hard[l];
  }
}

// ---------------- segment softmax-pool (VALS bf16 row-major) -> POOLED hi plane ----------
__global__ __launch_bounds__(256) void k_pool(const float* __restrict__ base,
    const us* __restrict__ VALSb, const int* __restrict__ seg_start,
    const int* __restrict__ seg_meta, us* __restrict__ Ph) {
  const int s = blockIdx.x, b = blockIdx.y, t = threadIdx.x;
  const int orow = b * Lz + s;
  const int nseg = seg_meta[b * 2], Lm = seg_meta[b * 2 + 1];
  int start = 0, end = 0;
  bool empty = true;
  if (s < nseg) {
    start = seg_start[b * (Lz + 1) + s];
    end = min(seg_start[b * (Lz + 1) + s + 1], Lm);
    empty = start >= end;
  }
  if (empty) { st_tiled(Ph, orow, t, 0); st_tiled(Ph, orow, t + 256, 0); return; }
  const int h = t >> 5, lane = t & 31;
  const float* bp = base + (size_t)b * Lz * NHz + h;
  float m = -1e30f;
  for (int l = start + lane; l < end; l += 32) m = fmaxf(m, bp[(size_t)l * NHz]);
  #pragma unroll
  for (int o = 16; o > 0; o >>= 1) m = fmaxf(m, __shfl_xor(m, o, 32));
  float den = 0.f;
  for (int l = start + lane; l < end; l += 32) den += expf(bp[(size_t)l * NHz] - m);
  #pragma unroll
  for (int o = 16; o > 0; o >>= 1) den += __shfl_xor(den, o, 32);
  float a0 = 0.f, a1 = 0.f;
  const us* vp = VALSb + (size_t)b * Lz * Dz + h * 64 + lane;
  for (int l = start; l < end; ++l) {
    float wgt = expf(bp[(size_t)l * NHz] - m);
    a0 += wgt * bf2f(vp[(size_t)l * Dz]);
    a1 += wgt * bf2f(vp[(size_t)l * Dz + 32]);
  }
  float inv = 1.f / den;
  st_tiled(Ph, orow, h * 64 + lane, f2bf(a0 * inv));
  st_tiled(Ph, orow, h * 64 + lane + 32, f2bf(a1 * inv));
}

extern "C" void kernel_launch(void* const* d_in, const int* in_sizes, int n_in,
                              void* d_out, int out_size, void* d_ws, size_t ws_size,
                              hipStream_t stream) {
  const float* hidden  = (const float*)d_in[0];
  const float* lengths = (const float*)d_in[1];
  const float* unoise  = (const float*)d_in[2];
  const float* W1  = (const float*)d_in[3];
  const float* b1  = (const float*)d_in[4];
  const float* W2  = (const float*)d_in[5];
  const float* b2  = (const float*)d_in[6];
  const float* Wq  = (const float*)d_in[7];
  const float* Wk  = (const float*)d_in[8];
  const float* simb   = (const float*)d_in[9];
  const float* lquery = (const float*)d_in[10];
  const float* Wpk = (const float*)d_in[11];
  const float* Wpv = (const float*)d_in[12];
  const float* Wpo = (const float*)d_in[13];
  const float* lng = (const float*)d_in[14];
  const float* lnb = (const float*)d_in[15];
  float* out = (float*)d_out;

  char* p = (char*)d_ws;
  const size_t SF = (size_t)Nz * Dz * 4;          // 12,288,000 B
  const size_t TP = (size_t)376 * 8192 * 2;       // 6,160,384 B
  const size_t WP = (size_t)32 * 8192 * 2;        // 524,288 B
  const size_t QP = (size_t)4 * 8192 * 2;         // 65,536 B (64x512 plane)
  float* M    = (float*)p; p += SF;
  float* PF   = (float*)p; p += SF;
  us* VALSb = (us*)p; p += TP;   // row-major bf16 (Nz*Dz*2 = 6,144,000 <= TP)
  us* Uh  = (us*)p; p += TP;
  us* Ul  = (us*)p; p += TP;
  us* T1h = (us*)p; p += TP;
  us* T1l = (us*)p; p += TP;
  us* Mh  = (us*)p; p += TP;
  us* Ml  = (us*)p; p += TP;
  us* HNh = (us*)p; p += TP;
  us* HNl = (us*)p; p += TP;
  us* Ph  = (us*)p; p += TP;
  us* W1h = (us*)p; p += WP;
  us* W1l = (us*)p; p += WP;
  us* W2h = (us*)p; p += WP;
  us* W2l = (us*)p; p += WP;
  us* Wpvh = (us*)p; p += WP;
  us* Wpoh = (us*)p; p += WP;
  us* WkTh = (us*)p; p += WP;
  us* WkTl = (us*)p; p += WP;
  us* WqTh = (us*)p; p += WP;
  us* WqTl = (us*)p; p += WP;
  us* Gth  = (us*)p; p += WP;
  us* Gtl  = (us*)p; p += WP;
  us* wqeh = (us*)p; p += QP;
  us* wqel = (us*)p; p += QP;
  float* probs  = (float*)p; p += 24064;
  float* base   = (float*)p; p += 192000;
  int* segst    = (int*)p;   p += 24064;
  int* segmeta  = (int*)p;   p += 256;

  const int G8 = 8 * 12 * 8;   // 768 swizzle slots (752 used), 64x64 tiles

  k_prep<<<288 + 375, 256, 0, stream>>>(hidden, lng, lnb, W1, W2, Wpv, Wpo, Wq, Wk,
      Wpk, lquery, W1h, W2h, Wpvh, Wpoh, W1l, W2l, WkTh, WkTl, WqTh, WqTl,
      wqeh, wqel, Uh, Ul, HNh, HNl);
  g_phase2<<<1694, 256, 0, stream>>>(Uh, Ul, W1h, W1l, b1, T1h, T1l,
      HNh, HNl, Wpvh, VALSb, WkTh, WkTl, WqTh, WqTl, Gth, Gtl, wqeh, wqel, base);
  g_w2<<<G8, 256, 0, stream>>>(T1h, T1l, W2h, W2l, b2, Uh, Ul, M, Mh, Ml);  // M(+planes)
  g_p<<<G8, 256, 0, stream>>>(Mh, Ml, Gth, Gtl, PF);             // P = M@Gt^T
  k_probs<<<dim3(375, Bz), 256, 0, stream>>>(PF, M, simb, probs);
  k_boundary<<<Bz, 256, 0, stream>>>(probs, unoise, lengths, segst, segmeta);
  k_pool<<<dim3(Lz, Bz), 256, 0, stream>>>(base, VALSb, segst, segmeta, Ph);
  g_out<<<G8, 256, 0, stream>>>(Ph, Wpoh, out);                  // out = POOLED@Wpo^T
}

// Round 16
// 211.148 us; speedup vs baseline: 1.0453x; 1.0053x over previous
//
#include <hip/hip_runtime.h>
#include <math.h>

#define Bz 4
#define Lz 1500
#define Dz 512
#define NHz 8
#define Nz (Bz*Lz)       // 6000 rows
#define PEPSf 1.1920929e-07f

typedef __bf16 bf16x8 __attribute__((ext_vector_type(8)));
typedef unsigned short u16x8 __attribute__((ext_vector_type(8)));
typedef float f32x4 __attribute__((ext_vector_type(4)));
typedef unsigned short us;

__device__ __forceinline__ us f2bf(float f) {
  unsigned u = __float_as_uint(f);
  return (us)((u + 0x7fffu + ((u >> 16) & 1u)) >> 16);
}
__device__ __forceinline__ float bf2f(us b) {
  return __uint_as_float(((unsigned)b) << 16);
}
// tiled bf16 plane: P[((row/16)*64 + col/8)*128 + (row%16)*8 + col%8]
__device__ __forceinline__ int ti_idx(int row, int col) {
  return (((row >> 4) * 64 + (col >> 3)) << 7) + ((row & 15) << 3) + (col & 7);
}
__device__ __forceinline__ void st_tiled(us* __restrict__ P, int row, int col, us v) {
  P[ti_idx(row, col)] = v;
}

// XCD-swizzled block decode (94 row groups of 64 rows; ncg col groups)
__device__ __forceinline__ bool decode_blk(int bx, int ncg, int& R, int& cg) {
  int xcd = bx & 7, v = bx >> 3;
  cg = v % ncg;
  R = (v / ncg) * 8 + xcd;
  return R < 94;
}

// ---------------- phase 1 (merged): weights->planes + wq_eff planes  AND  row prep -------
// blocks [0,288): weight conversion units; blocks [288, 288+375): row prep, 16 rows/block.
// 16-rows-per-block matches the 16x8 tile: each block writes COMPLETE 256B tiles (no
// cross-block partial-line write amplification — R7->R11 verified: 222.4 -> 210.7 us).
__global__ __launch_bounds__(256) void k_prep(
    const float* __restrict__ hidden,
    const float* __restrict__ g, const float* __restrict__ bb,
    const float* __restrict__ s0, const float* __restrict__ s1, const float* __restrict__ s2,
    const float* __restrict__ s3,  // W1, W2, Wpv, Wpo
    const float* __restrict__ Wq, const float* __restrict__ Wk,
    const float* __restrict__ Wpk, const float* __restrict__ lq,
    us* __restrict__ h0, us* __restrict__ h1, us* __restrict__ h2, us* __restrict__ h3,
    us* __restrict__ l0, us* __restrict__ l1,
    us* __restrict__ WkTh, us* __restrict__ WkTl, us* __restrict__ WqTh, us* __restrict__ WqTl,
    us* __restrict__ wqeh, us* __restrict__ wqel,
    us* __restrict__ Uh, us* __restrict__ Ul, us* __restrict__ HNh, us* __restrict__ HNl) {
  const int t = threadIdx.x;
  if (blockIdx.x < 288) {
    const int u = blockIdx.x, rt = u & 31, mat = u >> 5;
    if (mat == 8) {  // wqe[h,d] = sum_e lq[h*64+e]*Wpk[h*64+e,d] -> tiled hi/lo plane row h
      if (rt < 8) {
        for (int d = t; d < Dz; d += 256) {
          float acc = 0.f;
          for (int e = 0; e < 64; ++e)
            acc += lq[rt * 64 + e] * Wpk[(size_t)(rt * 64 + e) * Dz + d];
          us hb = f2bf(acc);
          st_tiled(wqeh, rt, d, hb);
          st_tiled(wqel, rt, d, f2bf(acc - bf2f(hb)));
        }
      }
      return;
    }
    const float* S; us* H; us* L = nullptr; bool tr = false;
    switch (mat) {
      case 0: S = s0; H = h0; L = l0; break;            // W1 hi/lo
      case 1: S = s1; H = h1; L = l1; break;            // W2 hi/lo
      case 2: S = s2; H = h2; break;                    // Wpv hi
      case 3: S = s3; H = h3; break;                    // Wpo hi
      case 4: S = Wk; H = WkTh; L = WkTl; tr = true; break;  // Wk^T hi/lo
      default: S = Wq; H = WqTh; L = WqTl; tr = true; break; // Wq^T hi/lo
    }
    for (int e = t; e < 8192; e += 256) {
      int mm = e >> 9, c = e & 511;
      float x = tr ? S[(size_t)c * 512 + (rt * 16 + mm)]
                   : S[(size_t)(rt * 16 + mm) * 512 + c];
      us hb = f2bf(x);
      int off = ((rt * 64 + (c >> 3)) << 7) + (mm << 3) + (c & 7);
      H[off] = hb;
      if (L) L[off] = f2bf(x - bf2f(hb));
    }
    return;
  }
  // ---- row prep: block = 16-row tile group; 16 threads per row; u16x8 (16B) stores ----
  const int rb = blockIdx.x - 288;            // 0..374
  const int rl = t >> 4, sub = t & 15;        // row-in-group, 16 threads/row
  const int row = rb * 16 + rl;
  __shared__ float gs[Dz], bs[Dz];
  gs[t] = g[t]; gs[t + 256] = g[t + 256];
  bs[t] = bb[t]; bs[t + 256] = bb[t + 256];
  __syncthreads();
  const f32x4* xp = (const f32x4*)(hidden + (size_t)row * Dz + sub * 32);
  f32x4 xv[8];
  #pragma unroll
  for (int i = 0; i < 8; ++i) xv[i] = xp[i];
  float s = 0.f, q = 0.f;
  #pragma unroll
  for (int i = 0; i < 8; ++i)
    #pragma unroll
    for (int j = 0; j < 4; ++j) { float v = xv[i][j]; s += v; q += v * v; }
  #pragma unroll
  for (int o = 1; o < 16; o <<= 1) { s += __shfl_xor(s, o, 16); q += __shfl_xor(q, o, 16); }
  float un = 1.f / fmaxf(sqrtf(q), 1e-8f);
  float mu = s * (1.f / 512.f);
  float var = fmaxf(q * (1.f / 512.f) - mu * mu, 0.f);
  float r = rsqrtf(var + 1e-5f);
  const int rowoff = rl << 3;
  #pragma unroll
  for (int ch = 0; ch < 4; ++ch) {
    const int c0 = sub * 32 + ch * 8;
    u16x8 uh, ul, hh, hl;
    #pragma unroll
    for (int k = 0; k < 8; ++k) {
      float xx = xv[ch * 2 + (k >> 2)][k & 3];
      float u = xx * un;
      us b = f2bf(u);
      uh[k] = b; ul[k] = f2bf(u - bf2f(b));
      float hn = (xx - mu) * r * gs[c0 + k] + bs[c0 + k];
      us nb = f2bf(hn);
      hh[k] = nb; hl[k] = f2bf(hn - bf2f(nb));
    }
    const int off = ((rb * 64 + sub * 4 + ch) << 7) + rowoff;   // = ti_idx(row, c0)
    *(u16x8*)(Uh + off) = uh;
    *(u16x8*)(Ul + off) = ul;
    *(u16x8*)(HNh + off) = hh;
    *(u16x8*)(HNl + off) = hl;
  }
}

// ---------------- direct-layout MFMA GEMM body: 64x64 block tile, 32x32 wave tile --------
// no LDS, 1-deep register prefetch, unroll-2 (ledger: full unroll 220.7, unroll-2 210.7;
// LDS-staged epilogue neutral R15 — blocks already own complete tiles).
// outBase: skinny-output mode — stores v*0.125 to outBase[row*NHz+col] for col<NHz only.
template<int SPLIT>
__device__ __forceinline__ void gemm_body(
    const us* __restrict__ Ah, const us* __restrict__ Al,
    const us* __restrict__ Bh, const us* __restrict__ Bl,
    const float* __restrict__ bias,
    const us* __restrict__ addH, const us* __restrict__ addL, int doGelu,
    float* __restrict__ outF, us* __restrict__ outR,
    us* __restrict__ outH, us* __restrict__ outL, float* __restrict__ outBase,
    int R, int cg, int colbase, int Nrows) {
  const int t = threadIdx.x, w = t >> 6, l = t & 63;
  const int m = l & 15, q = l >> 4;
  const int wr = w & 1, wc = w >> 1;      // wave half-row / half-col within 64x64 tile
  const int laneoff = q * 128 + m * 8;
  const int nrtm1 = (Nrows >> 4) - 1;

  const u16x8* pa[2]; const u16x8* pal[2];
  const u16x8* pb[2]; const u16x8* pbl[2];
  #pragma unroll
  for (int i = 0; i < 2; ++i) {
    int rt = min(R * 4 + wr * 2 + i, nrtm1);   // tail clamp; stores guarded
    pa[i] = (const u16x8*)(Ah + (size_t)rt * 8192 + laneoff);
    if (SPLIT == 3) pal[i] = (const u16x8*)(Al + (size_t)rt * 8192 + laneoff);
  }
  #pragma unroll
  for (int j = 0; j < 2; ++j) {
    int ct = cg * 4 + wc * 2 + j;
    pb[j] = (const u16x8*)(Bh + (size_t)ct * 8192 + laneoff);
    if (SPLIT == 3) pbl[j] = (const u16x8*)(Bl + (size_t)ct * 8192 + laneoff);
  }

  u16x8 bAh[2][2], bAl[2][2], bBh[2][2], bBl[2][2];
  #pragma unroll
  for (int i = 0; i < 2; ++i) {
    bAh[0][i] = pa[i][0];
    if (SPLIT == 3) bAl[0][i] = pal[i][0];
  }
  #pragma unroll
  for (int j = 0; j < 2; ++j) {
    bBh[0][j] = pb[j][0];
    if (SPLIT == 3) bBl[0][j] = pbl[j][0];
  }

  f32x4 acc[2][2];
  #pragma unroll
  for (int i = 0; i < 2; ++i)
    #pragma unroll
    for (int j = 0; j < 2; ++j) acc[i][j] = (f32x4){0.f, 0.f, 0.f, 0.f};

  #pragma unroll 2
  for (int s = 0; s < 16; ++s) {
    const int cur = s & 1, nxt = cur ^ 1;
    const int sn = (s + 1) & 15;      // wrap: final iter reloads step 0 (discarded)
    #pragma unroll
    for (int i = 0; i < 2; ++i) {
      bAh[nxt][i] = pa[i][sn * 64];
      if (SPLIT == 3) bAl[nxt][i] = pal[i][sn * 64];
    }
    #pragma unroll
    for (int j = 0; j < 2; ++j) {
      bBh[nxt][j] = pb[j][sn * 64];
      if (SPLIT == 3) bBl[nxt][j] = pbl[j][sn * 64];
    }
    #pragma unroll
    for (int i = 0; i < 2; ++i)
      #pragma unroll
      for (int j = 0; j < 2; ++j) {
        bf16x8 a = __builtin_bit_cast(bf16x8, bAh[cur][i]);
        bf16x8 b = __builtin_bit_cast(bf16x8, bBh[cur][j]);
        acc[i][j] = __builtin_amdgcn_mfma_f32_16x16x32_bf16(a, b, acc[i][j], 0, 0, 0);
        if (SPLIT == 3) {
          bf16x8 al_ = __builtin_bit_cast(bf16x8, bAl[cur][i]);
          bf16x8 bl_ = __builtin_bit_cast(bf16x8, bBl[cur][j]);
          acc[i][j] = __builtin_amdgcn_mfma_f32_16x16x32_bf16(a, bl_, acc[i][j], 0, 0, 0);
          acc[i][j] = __builtin_amdgcn_mfma_f32_16x16x32_bf16(al_, b, acc[i][j], 0, 0, 0);
        }
      }
  }

  // epilogue: C/D layout col = m, row = q*4 + r
  const int row0 = R * 64 + wr * 32;
  const int col0 = colbase + wc * 32;
  #pragma unroll
  for (int i = 0; i < 2; ++i) {
    #pragma unroll
    for (int r = 0; r < 4; ++r) {
      const int grow = row0 + i * 16 + q * 4 + r;
      if (grow >= Nrows) continue;
      #pragma unroll
      for (int j = 0; j < 2; ++j) {
        const int gcol = col0 + j * 16 + m;
        float v = acc[i][j][r];
        if (outBase) {   // skinny base output: only first NHz cols are real
          if (gcol < NHz) outBase[(size_t)grow * NHz + gcol] = v * 0.125f;
          continue;
        }
        if (bias)   v += bias[gcol];
        if (addH) {
          int ai = ti_idx(grow, gcol);
          v += bf2f(addH[ai]) + bf2f(addL[ai]);
        }
        if (doGelu) v = 0.5f * v * (1.f + erff(v * 0.70710678118654752f));
        if (outF) outF[(size_t)grow * Dz + gcol] = v;
        if (outR) outR[(size_t)grow * Dz + gcol] = f2bf(v);
        if (outH) {
          us hb = f2bf(v);
          st_tiled(outH, grow, gcol, hb);
          if (outL) st_tiled(outL, grow, gcol, f2bf(v - bf2f(hb)));
        }
      }
    }
  }
}

// ---------------- phase 2: T1 (u<768), VALS (u<1536), Gt (u<1600), base GEMM (u<1694) ----
// base = (HN split-3) @ (wqe plane)^T, 64 cols computed, 8 stored.
__global__ __launch_bounds__(256, 4) void g_phase2(
    const us* Uh, const us* Ul, const us* W1h, const us* W1l, const float* b1, us* T1h, us* T1l,
    const us* HNh, const us* HNl, const us* Wpvh, us* VALSb,
    const us* WkTh, const us* WkTl, const us* WqTh, const us* WqTl, us* Gth, us* Gtl,
    const us* wqeh, const us* wqel, float* base) {
  const int u = blockIdx.x;
  if (u < 768) {
    int R, c;
    if (decode_blk(u, 8, R, c))
      gemm_body<3>(Uh, Ul, W1h, W1l, b1, nullptr, nullptr, 1,
                   nullptr, nullptr, T1h, T1l, nullptr, R, c, c * 64, Nz);
    return;
  }
  if (u < 1536) {
    int R, c;
    if (decode_blk(u - 768, 8, R, c))
      gemm_body<1>(HNh, nullptr, Wpvh, nullptr, nullptr, nullptr, nullptr, 0,
                   nullptr, VALSb, nullptr, nullptr, nullptr, R, c, c * 64, Nz);
    return;
  }
  if (u < 1600) {
    int bx = u - 1536;
    gemm_body<3>(WkTh, WkTl, WqTh, WqTl, nullptr, nullptr, nullptr, 0,
                 nullptr, nullptr, Gth, Gtl, nullptr, bx >> 3, bx & 7, (bx & 7) * 64, 512);
    return;
  }
  {  // base GEMM: 94 uniform blocks, single col group
    int R = u - 1600;
    if (R < 94)
      gemm_body<3>(HNh, HNl, wqeh, wqel, nullptr, nullptr, nullptr, 0,
                   nullptr, nullptr, nullptr, nullptr, base, R, 0, 0, Nz);
  }
}

// M = T1@W2^T + b2 + U  (fp32 + tiled hi/lo planes)
__global__ __launch_bounds__(256, 4) void g_w2(
    const us* T1h, const us* T1l, const us* W2h, const us* W2l, const float* b2,
    const us* Uh, const us* Ul, float* M, us* Mh, us* Ml) {
  int R, cg;
  if (!decode_blk(blockIdx.x, 8, R, cg)) return;
  gemm_body<3>(T1h, T1l, W2h, W2l, b2, Uh, Ul, 0, M, nullptr, Mh, Ml, nullptr,
               R, cg, cg * 64, Nz);
}

// P = M @ Gt^T   (normalization folded into k_probs)
__global__ __launch_bounds__(256, 4) void g_p(
    const us* Mh, const us* Ml, const us* Gth, const us* Gtl, float* P) {
  int R, cg;
  if (!decode_blk(blockIdx.x, 8, R, cg)) return;
  gemm_body<3>(Mh, Ml, Gth, Gtl, nullptr, nullptr, nullptr, 0,
               P, nullptr, nullptr, nullptr, nullptr, R, cg, cg * 64, Nz);
}

// out = POOLED@Wpo^T with data-dependent zero fast path: rows with s >= nseg have Ph == 0
// (k_pool zeroes empty segments) -> output exactly zero; skip the K-loop, store zeros.
__global__ __launch_bounds__(256, 4) void g_out(
    const us* Ph, const us* Wpoh, const int* __restrict__ segmeta, float* out) {
  int R, cg;
  if (!decode_blk(blockIdx.x, 8, R, cg)) return;
  const int r0 = R * 64, r1 = min(R * 64 + 63, Nz - 1);
  const int b0 = r0 / Lz, b1 = r1 / Lz;
  bool allz = true;
  for (int b = b0; b <= b1; ++b) {
    int smin = max(r0, b * Lz) - b * Lz;        // first segment index of this batch in range
    if (smin < segmeta[b * 2]) { allz = false; break; }
  }
  if (allz) {
    const int t = threadIdx.x;
    for (int e = t; e < 1024; e += 256) {       // 64 rows x 16 f32x4 per row
      int rr = e >> 4, cc = e & 15;
      int grow = r0 + rr;
      if (grow < Nz)
        *(f32x4*)(out + (size_t)grow * Dz + cg * 64 + cc * 4) = (f32x4){0.f, 0.f, 0.f, 0.f};
    }
    return;
  }
  gemm_body<1>(Ph, nullptr, Wpoh, nullptr, nullptr, nullptr, nullptr, 0,
               out, nullptr, nullptr, nullptr, nullptr, R, cg, cg * 64, Nz);
}

// ---------------- cos(l) = un_l * un_{l+1} * dot(P_l, M_{l+1}) -> probs ----------------
__global__ __launch_bounds__(256) void k_probs(const float* __restrict__ P,
    const float* __restrict__ M, const float* __restrict__ simb,
    float* __restrict__ probs) {
  const int w = threadIdx.x >> 6, t = threadIdx.x & 63;
  const int l = blockIdx.x * 4 + w, b = blockIdx.y;
  if (l >= Lz) return;
  if (l == Lz - 1) { if (t == 0) probs[(size_t)b * Lz + l] = 0.f; return; }
  const float* pp = P + ((size_t)b * Lz + l) * Dz;
  const float* m0 = M + ((size_t)b * Lz + l) * Dz;
  const float* m1 = M + ((size_t)b * Lz + l + 1) * Dz;
  float accd = 0.f, q0 = 0.f, q1 = 0.f;
  for (int i = t; i < Dz; i += 64) {
    float a = pp[i], x0 = m0[i], x1 = m1[i];
    accd += a * x1; q0 += x0 * x0; q1 += x1 * x1;
  }
  #pragma unroll
  for (int o = 32; o > 0; o >>= 1) {
    accd += __shfl_xor(accd, o, 64);
    q0 += __shfl_xor(q0, o, 64);
    q1 += __shfl_xor(q1, o, 64);
  }
  if (t == 0) {
    float un0 = 1.f / fmaxf(sqrtf(q0), 1e-8f);
    float un1 = 1.f / fmaxf(sqrtf(q1), 1e-8f);
    float cosv = accd * un0 * un1;
    float p = (1.f - (cosv + simb[0])) * 0.5f;
    probs[(size_t)b * Lz + l] = fminf(fmaxf(p, 0.f), 1.f);
  }
}

// ---------------- boundaries + scan (shuffle-based scan) ----------------
__global__ __launch_bounds__(256) void k_boundary(const float* __restrict__ probs,
    const float* __restrict__ un, const float* __restrict__ lengths,
    int* __restrict__ seg_start, int* __restrict__ seg_meta) {
  const int b = blockIdx.x, t = threadIdx.x;
  __shared__ float hard[Lz];
  __shared__ float ws4[4];
  __shared__ float wsum[4];
  const float len = lengths[b];
  const int valid_len = min((int)(len * (Lz + 1)) - 1, Lz);
  const int Lm = (int)(len * Lz);
  const bool trunc = valid_len < Lz;
  for (int l = t; l < Lz; l += 256) {
    float p = probs[(size_t)b * Lz + l];
    p = fminf(fmaxf(p, PEPSf), 1.f - PEPSf);
    float u = un[(size_t)b * Lz + l];
    u = fminf(fmaxf(u, PEPSf), 1.f - PEPSf);
    float z = logf(p) - log1pf(-p) + logf(u) - log1pf(-u);
    float soft = 1.f / (1.f + expf(-z));
    float hd = soft > 0.5f ? 1.f : 0.f;
    if (trunc && l >= valid_len) hd = (l == valid_len) ? 1.f : 0.f;
    hard[l] = hd;
  }
  __syncthreads();
  float sm = 0.f;
  for (int l = t; l < Lz; l += 256) sm += hard[l];
  #pragma unroll
  for (int o = 32; o > 0; o >>= 1) sm += __shfl_xor(sm, o, 64);
  if ((t & 63) == 0) ws4[t >> 6] = sm;
  __syncthreads();
  float total = ws4[0] + ws4[1] + ws4[2] + ws4[3];
  if (total == 0.f && t == 0) hard[min(valid_len, Lz - 1)] = 1.f;
  __syncthreads();
  const int l0 = t * 6;
  float loc = 0.f;
  for (int i = 0; i < 6; ++i) { int l = l0 + i; if (l < Lz) loc += hard[l]; }
  const int wid = t >> 6, lane = t & 63;
  float v = loc;
  #pragma unroll
  for (int o = 1; o < 64; o <<= 1) {
    float n = __shfl_up(v, o, 64);
    if (lane >= o) v += n;
  }
  if (lane == 63) wsum[wid] = v;
  __syncthreads();
  float woff = 0.f;
  for (int ww = 0; ww < wid; ++ww) woff += wsum[ww];
  float run = v + woff - loc;          // exclusive prefix (exact: integer-valued fp32)
  for (int i = 0; i < 6; ++i) {
    int l = l0 + i; if (l >= Lz) break;
    int seg = (int)(run + 0.5f);
    if (l == 0) seg_start[b * (Lz + 1) + 0] = 0;
    else if (hard[l - 1] > 0.5f) seg_start[b * (Lz + 1) + seg] = l;
    if (l == Lz - 1) {
      int nseg = seg + 1;
      seg_meta[b * 2 + 0] = nseg;
      seg_meta[b * 2 + 1] = Lm;
      seg_start[b * (Lz + 1) + nseg] = Lz;
    }
    run += hard[l];
  }
}

// ---------------- segment softmax-pool (VALS bf16 row-major) -> POOLED hi plane ----------
__global__ __launch_bounds__(256) void k_pool(const float* __restrict__ base,
    const us* __restrict__ VALSb, const int* __restrict__ seg_start,
    const int* __restrict__ seg_meta, us* __restrict__ Ph) {
  const int s = blockIdx.x, b = blockIdx.y, t = threadIdx.x;
  const int orow = b * Lz + s;
  const int nseg = seg_meta[b * 2], Lm = seg_meta[b * 2 + 1];
  int start = 0, end = 0;
  bool empty = true;
  if (s < nseg) {
    start = seg_start[b * (Lz + 1) + s];
    end = min(seg_start[b * (Lz + 1) + s + 1], Lm);
    empty = start >= end;
  }
  if (empty) { st_tiled(Ph, orow, t, 0); st_tiled(Ph, orow, t + 256, 0); return; }
  const int h = t >> 5, lane = t & 31;
  const float* bp = base + (size_t)b * Lz * NHz + h;
  float m = -1e30f;
  for (int l = start + lane; l < end; l += 32) m = fmaxf(m, bp[(size_t)l * NHz]);
  #pragma unroll
  for (int o = 16; o > 0; o >>= 1) m = fmaxf(m, __shfl_xor(m, o, 32));
  float den = 0.f;
  for (int l = start + lane; l < end; l += 32) den += expf(bp[(size_t)l * NHz] - m);
  #pragma unroll
  for (int o = 16; o > 0; o >>= 1) den += __shfl_xor(den, o, 32);
  float a0 = 0.f, a1 = 0.f;
  const us* vp = VALSb + (size_t)b * Lz * Dz + h * 64 + lane;
  for (int l = start; l < end; ++l) {
    float wgt = expf(bp[(size_t)l * NHz] - m);
    a0 += wgt * bf2f(vp[(size_t)l * Dz]);
    a1 += wgt * bf2f(vp[(size_t)l * Dz + 32]);
  }
  float inv = 1.f / den;
  st_tiled(Ph, orow, h * 64 + lane, f2bf(a0 * inv));
  st_tiled(Ph, orow, h * 64 + lane + 32, f2bf(a1 * inv));
}

extern "C" void kernel_launch(void* const* d_in, const int* in_sizes, int n_in,
                              void* d_out, int out_size, void* d_ws, size_t ws_size,
                              hipStream_t stream) {
  const float* hidden  = (const float*)d_in[0];
  const float* lengths = (const float*)d_in[1];
  const float* unoise  = (const float*)d_in[2];
  const float* W1  = (const float*)d_in[3];
  const float* b1  = (const float*)d_in[4];
  const float* W2  = (const float*)d_in[5];
  const float* b2  = (const float*)d_in[6];
  const float* Wq  = (const float*)d_in[7];
  const float* Wk  = (const float*)d_in[8];
  const float* simb   = (const float*)d_in[9];
  const float* lquery = (const float*)d_in[10];
  const float* Wpk = (const float*)d_in[11];
  const float* Wpv = (const float*)d_in[12];
  const float* Wpo = (const float*)d_in[13];
  const float* lng = (const float*)d_in[14];
  const float* lnb = (const float*)d_in[15];
  float* out = (float*)d_out;

  char* p = (char*)d_ws;
  const size_t SF = (size_t)Nz * Dz * 4;          // 12,288,000 B
  const size_t TP = (size_t)376 * 8192 * 2;       // 6,160,384 B
  const size_t WP = (size_t)32 * 8192 * 2;        // 524,288 B
  const size_t QP = (size_t)4 * 8192 * 2;         // 65,536 B (64x512 plane)
  float* M    = (float*)p; p += SF;
  float* PF   = (float*)p; p += SF;
  us* VALSb = (us*)p; p += TP;   // row-major bf16 (Nz*Dz*2 = 6,144,000 <= TP)
  us* Uh  = (us*)p; p += TP;
  us* Ul  = (us*)p; p += TP;
  us* T1h = (us*)p; p += TP;
  us* T1l = (us*)p; p += TP;
  us* Mh  = (us*)p; p += TP;
  us* Ml  = (us*)p; p += TP;
  us* HNh = (us*)p; p += TP;
  us* HNl = (us*)p; p += TP;
  us* Ph  = (us*)p; p += TP;
  us* W1h = (us*)p; p += WP;
  us* W1l = (us*)p; p += WP;
  us* W2h = (us*)p; p += WP;
  us* W2l = (us*)p; p += WP;
  us* Wpvh = (us*)p; p += WP;
  us* Wpoh = (us*)p; p += WP;
  us* WkTh = (us*)p; p += WP;
  us* WkTl = (us*)p; p += WP;
  us* WqTh = (us*)p; p += WP;
  us* WqTl = (us*)p; p += WP;
  us* Gth  = (us*)p; p += WP;
  us* Gtl  = (us*)p; p += WP;
  us* wqeh = (us*)p; p += QP;
  us* wqel = (us*)p; p += QP;
  float* probs  = (float*)p; p += 24064;
  float* base   = (float*)p; p += 192000;
  int* segst    = (int*)p;   p += 24064;
  int* segmeta  = (int*)p;   p += 256;

  const int G8 = 8 * 12 * 8;   // 768 swizzle slots (752 used), 64x64 tiles

  k_prep<<<288 + 375, 256, 0, stream>>>(hidden, lng, lnb, W1, W2, Wpv, Wpo, Wq, Wk,
      Wpk, lquery, W1h, W2h, Wpvh, Wpoh, W1l, W2l, WkTh, WkTl, WqTh, WqTl,
      wqeh, wqel, Uh, Ul, HNh, HNl);
  g_phase2<<<1694, 256, 0, stream>>>(Uh, Ul, W1h, W1l, b1, T1h, T1l,
      HNh, HNl, Wpvh, VALSb, WkTh, WkTl, WqTh, WqTl, Gth, Gtl, wqeh, wqel, base);
  g_w2<<<G8, 256, 0, stream>>>(T1h, T1l, W2h, W2l, b2, Uh, Ul, M, Mh, Ml);  // M(+planes)
  g_p<<<G8, 256, 0, stream>>>(Mh, Ml, Gth, Gtl, PF);             // P = M@Gt^T
  k_probs<<<dim3(375, Bz), 256, 0, stream>>>(PF, M, simb, probs);
  k_boundary<<<Bz, 256, 0, stream>>>(probs, unoise, lengths, segst, segmeta);
  k_pool<<<dim3(Lz, Bz), 256, 0, stream>>>(base, VALSb, segst, segmeta, Ph);
  g_out<<<G8, 256, 0, stream>>>(Ph, Wpoh, segmeta, out);         // out = POOLED@Wpo^T
}